// Round 1
// baseline (498.486 us; speedup 1.0000x reference)
//
#include <hip/hip_runtime.h>
#include <hip/hip_bf16.h>

#define HID   51
#define MR    208          // 204 gate rows + y row (204) padded to 13 tiles of 16
#define SEQT  999
#define CH    111          // 999 = 9 * 111
#define NCH   9
#define EPB   16           // batch elements per block -> 256 blocks, full-width lanes
#define XST   17           // x/y LDS stride (EPB+1)
#define NTH   832          // 13 waves: one 16-row tile each; wave 12 = tile 12 + service
#define BSTR  72           // bcol row stride in halves (144 B: 16B-aligned, free 2-way)

typedef __attribute__((ext_vector_type(8))) short  short8;   // 8 bf16 = 4 VGPRs
typedef __attribute__((ext_vector_type(4))) float  floatx4;

// A_ext[208][64] bf16, row r = 4u+gate, PRE-SCALED by -log2(e) (i,f,o) or
// -2*log2(e) (g) so the MFMA output is directly an exp2 argument.
//   rows 0..203: cols 0..50 <- W_hh[gate*51+u][k], col 51 <- W_ih[gate*51+u]
//   row  204   : cols 0..50 <- W_fc[k] UNSCALED  (y_{t-1} falls out of the MFMA)
__global__ void prep_kernel(const float* __restrict__ W_hh,
                            const float* __restrict__ W_ih,
                            const float* __restrict__ W_fc,
                            __hip_bfloat16* __restrict__ A_ext)
{
    const float K1 = 1.442695040889f;
    int idx = blockIdx.x * blockDim.x + threadIdx.x;
    if (idx >= MR * 64) return;
    int r = idx >> 6, k = idx & 63;
    int u = r >> 2, gate = r & 3;
    float v = 0.f;
    if (r == 204) {
        if (k < HID) v = W_fc[k];
    } else if (u < HID) {
        float s = (gate == 2) ? (-2.f * K1) : (-K1);
        if (k < HID)      v = s * W_hh[(gate * HID + u) * HID + k];
        else if (k == 51) v = s * W_ih[gate * HID + u];
    }
    A_ext[idx] = __float2bfloat16(v);
}

__launch_bounds__(NTH)
__global__ void lstm_mfma_kernel(const float* __restrict__ x,
                                 const float* __restrict__ b_ih,
                                 const float* __restrict__ b_hh,
                                 const float* __restrict__ b_fc,
                                 const __hip_bfloat16* __restrict__ A_ext,
                                 float* __restrict__ out)
{
    __shared__ __hip_bfloat16 bcol[2][16 * BSTR];
    __shared__ float x_lds[(CH + 1) * XST];   // +1 lookahead for row-51 prewrite
    __shared__ float y_lds[CH * XST];         // slot tt holds y[t0 + tt - 1]

    const int tid  = threadIdx.x;
    const int w    = tid >> 6;    // tile index 0..12
    const int lane = tid & 63;
    const int e    = lane & 15;   // MFMA col — all 16 live
    const int g4   = lane >> 4;   // lane group
    const int e0   = blockIdx.x * EPB;

    // wave w owns tile w: units u = 4w+g4.  u==51 (w12,g4==3) is the y row.
    const int  u    = 4 * w + g4;
    const bool yln  = (u == 51);
    const bool xsv  = (w == 12) && (g4 == 0);
    const int  wrow = (u < HID) ? u : 63;     // y lanes dump (write 0) to row 63

    const float K1  = 1.442695040889f;
    const float K2N = -2.885390081777f;      // -2*log2(e)

    short8  A0, A1;
    floatx4 bq = {0.f, 0.f, 0.f, 0.f};
    float   cs = 0.f;                         // cell state (pre-scaled by K2N)

    {
        int m = w * 16 + e;
        A0 = *(const short8*)&A_ext[m * 64 + g4 * 8];
        A1 = *(const short8*)&A_ext[m * 64 + 32 + g4 * 8];
    }
    if (u < HID) {
#pragma unroll
        for (int gg = 0; gg < 4; ++gg) {
            float s = (gg == 2) ? (-2.f * K1) : (-K1);
            bq[gg] = s * (b_ih[gg * HID + u] + b_hh[gg * HID + u]);
        }
    }

    for (int i = tid; i < 16 * BSTR; i += NTH) {
        bcol[0][i] = __float2bfloat16(0.f);
        bcol[1][i] = __float2bfloat16(0.f);
    }
    __syncthreads();   // zero-init fully ordered before x0 seed
    if (tid < EPB)
        bcol[0][tid * BSTR + 51] = __float2bfloat16(x[(size_t)(e0 + tid) * SEQT]);
    const float bfc = b_fc[0];

    __syncthreads();

    for (int tc = 0; tc < NCH; ++tc) {
        const int t0 = tc * CH;
        for (int i2 = tid; i2 < (CH + 1) * EPB; i2 += NTH) {
            int ee = i2 / (CH + 1), tt = i2 % (CH + 1);
            int t = t0 + tt;
            x_lds[tt * XST + ee] = (t < SEQT) ? x[(size_t)(e0 + ee) * SEQT + t] : 0.f;
        }
        __syncthreads();

        for (int tt = 0; tt < CH; ++tt) {
            const int t  = t0 + tt;
            const int rp = t & 1, wp = rp ^ 1;

            short8 B0 = *(const short8*)&bcol[rp][e * BSTR + g4 * 8];
            short8 B1 = *(const short8*)&bcol[rp][e * BSTR + 32 + g4 * 8];

            floatx4 acc = __builtin_amdgcn_mfma_f32_16x16x32_bf16(A0, B0, bq, 0, 0, 0);
            acc = __builtin_amdgcn_mfma_f32_16x16x32_bf16(A1, B1, acc, 0, 0, 0);

            float Ei = __builtin_amdgcn_exp2f(acc[0]);
            float Ef = __builtin_amdgcn_exp2f(acc[1]);
            float Eg = __builtin_amdgcn_exp2f(acc[2]);
            float Eo = __builtin_amdgcn_exp2f(acc[3]);

            // merged-denominator cell update: ONE rcp for the (i,f,g) gates.
            //   c' = c/(1+Ef) + K2N*(1-Eg)/((1+Ei)(1+Eg))
            //      = (c*P + K2N*(1-Eg)*F1) / (F1*P),  P=(1+Ei)(1+Eg), F1=1+Ef
            float P  = fmaf(Ei, Eg, (Ei + Eg) + 1.f);
            float F1 = 1.f + Ef;
            float R  = __builtin_amdgcn_rcpf(F1 * P);
            cs = fmaf(cs, P, K2N * ((1.f - Eg) * F1)) * R;

            float Ec  = __builtin_amdgcn_exp2f(cs);
            float Roc = __builtin_amdgcn_rcpf(fmaf(Eo, Ec, (Eo + Ec) + 1.f));
            float h   = (1.f - Ec) * Roc;

            bcol[wp][e * BSTR + wrow] = __float2bfloat16((u < HID) ? h : 0.f);
            if (yln) y_lds[tt * XST + e] = acc[0] + bfc;   // y[t-1], free
            if (xsv) bcol[wp][e * BSTR + 51] =
                         __float2bfloat16(x_lds[(tt + 1) * XST + e]);

            __syncthreads();   // the ONE barrier per step
        }
        __syncthreads();

        // flush y[t0-1 .. t0+CH-2] (slot tt <-> t0+tt-1); skip t = -1
        for (int i2 = tid; i2 < CH * EPB; i2 += NTH) {
            int ee = i2 / CH, tt = i2 % CH;
            int t = t0 + tt - 1;
            if (t >= 0)
                out[(size_t)(e0 + ee) * SEQT + t] = y_lds[tt * XST + ee];
        }
        __syncthreads();
    }

    // epilogue: y[998] from one extra MFMA pass over h_998 (in bcol[1])
    if (w == 12) {
        short8 B0 = *(const short8*)&bcol[1][e * BSTR + g4 * 8];
        short8 B1 = *(const short8*)&bcol[1][e * BSTR + 32 + g4 * 8];
        floatx4 acc = __builtin_amdgcn_mfma_f32_16x16x32_bf16(A0, B0, bq, 0, 0, 0);
        acc = __builtin_amdgcn_mfma_f32_16x16x32_bf16(A1, B1, acc, 0, 0, 0);
        if (g4 == 3)
            out[(size_t)(e0 + e) * SEQT + (SEQT - 1)] = acc[0] + bfc;
    }
}

extern "C" void kernel_launch(void* const* d_in, const int* in_sizes, int n_in,
                              void* d_out, int out_size, void* d_ws, size_t ws_size,
                              hipStream_t stream) {
    const float* x    = (const float*)d_in[0];
    const float* W_ih = (const float*)d_in[1];
    const float* W_hh = (const float*)d_in[2];
    const float* b_ih = (const float*)d_in[3];
    const float* b_hh = (const float*)d_in[4];
    const float* W_fc = (const float*)d_in[5];
    const float* b_fc = (const float*)d_in[6];
    float* out = (float*)d_out;

    __hip_bfloat16* A_ext = (__hip_bfloat16*)d_ws;   // 208*64*2 = 26.6 KB

    prep_kernel<<<(MR * 64 + 255) / 256, 256, 0, stream>>>(W_hh, W_ih, W_fc, A_ext);
    lstm_mfma_kernel<<<4096 / EPB, NTH, 0, stream>>>(x, b_ih, b_hh,
                                                     b_fc, A_ext, out);
}